// Round 1
// 1457.679 us; speedup vs baseline: 2.2605x; 2.2605x over previous
//
#include <hip/hip_runtime.h>
#include <stdint.h>

#define T_LEN 1024
#define H 256
#define B_SZ 128

typedef __attribute__((ext_vector_type(8))) __bf16 bf16x8;
typedef __attribute__((ext_vector_type(4))) float f32x4;

__device__ __forceinline__ unsigned short f32_to_bf16_rne(float f) {
  union { float f; unsigned int u; } c{f};
  unsigned int r = 0x7FFFu + ((c.u >> 16) & 1u);
  c.u += r;
  return (unsigned short)(c.u >> 16);
}
__device__ __forceinline__ float bf16_to_f32(unsigned short h) {
  union { unsigned int u; float f; } c{(unsigned int)h << 16};
  return c.f;
}

// DPP quad-perm add: x + x[lane ^ 1] (CTRL=0xB1) or x + x[lane ^ 2] (CTRL=0x4E)
template <int CTRL>
__device__ __forceinline__ float dpp_xor_add(float x) {
  int v = __builtin_amdgcn_update_dpp(0, __float_as_int(x), CTRL, 0xF, 0xF, true);
  return x + __int_as_float(v);
}

// x + x[lane ^ 32] without touching the LDS pipe.
__device__ __forceinline__ float xor32_add(float x) {
#if __has_builtin(__builtin_amdgcn_permlane32_swap)
  const int xi = __float_as_int(x);
  auto r = __builtin_amdgcn_permlane32_swap(xi, xi, false, false);
  return __int_as_float((int)r[0]) + __int_as_float((int)r[1]);
#else
  return x + __shfl_xor(x, 32, 64);
#endif
}

// ---------------------------------------------------------------- h0 kernel
// h0 = relu(relu(rowsum(W1)+b1) @ W2.T + b2)  -- identical for every batch.
__global__ void h0_kernel(const float* __restrict__ W1, const float* __restrict__ b1,
                          const float* __restrict__ W2, const float* __restrict__ b2,
                          float* __restrict__ h0) {
  __shared__ float hid[64];
  const int tid = threadIdx.x;
  if (tid < 64) hid[tid] = fmaxf(W1[tid * 2 + 0] + W1[tid * 2 + 1] + b1[tid], 0.0f);
  __syncthreads();
  float acc = b2[tid];
  #pragma unroll
  for (int j = 0; j < 64; ++j) acc = fmaf(W2[tid * 64 + j], hid[j], acc);
  h0[tid] = fmaxf(acc, 0.0f);
}

// ---------------------------------------------------------------- recurrence
// One block per batch, 512 threads (8 waves, 2/SIMD).
// k-split matvec: lane owns 4 outputs (o = w*32 + g + 8s) over one 32-wide
// k-eighth (q = (lane&3) | ((lane>>5)<<2)). Weights: 32 float4 = 128 VGPRs,
// truly register-resident (small arrays -> SROA promotes).
// h lives ping-ponged in LDS, XOR-swizzled at float4 granularity so the 8
// k-eighth address groups of one ds_read_b128 hit disjoint bank quads.
// Partial reduction across the 8 eighths: dpp xor1 + dpp xor2 + permlane32
// (all VALU, no LDS). One raw s_barrier per step (lgkmcnt-only drain: the
// per-step global p store is NOT drained, unlike __syncthreads).
__global__ __launch_bounds__(512, 2) void rnn_kernel(
    const float* __restrict__ inputs, const float* __restrict__ W_ih,
    const float* __restrict__ W_hh, const float* __restrict__ h0,
    float* __restrict__ p_out) {
  __shared__ float hbuf[2][H];
  const int b = blockIdx.x;
  const int tid = threadIdx.x;
  const int lane = tid & 63;
  const int w = tid >> 6;           // wave 0..7 -> output block [w*32, w*32+32)
  const int qlow = lane & 3;
  const int q2 = lane >> 5;         // 0..1
  const int q = qlow | (q2 << 2);   // k-eighth 0..7 -> k in [q*32, q*32+32)
  const int g = (lane >> 2) & 7;    // 0..7

  // ---- weights: rows o_s = w*32 + g + 8s, cols [q*32, q*32+32) ----
  float4 wv0[8], wv1[8], wv2[8], wv3[8];
  {
    const float* Wq = W_hh + (size_t)q * 32;
    const float4* r0 = reinterpret_cast<const float4*>(Wq + (size_t)(w * 32 + g +  0) * H);
    const float4* r1 = reinterpret_cast<const float4*>(Wq + (size_t)(w * 32 + g +  8) * H);
    const float4* r2 = reinterpret_cast<const float4*>(Wq + (size_t)(w * 32 + g + 16) * H);
    const float4* r3 = reinterpret_cast<const float4*>(Wq + (size_t)(w * 32 + g + 24) * H);
    #pragma unroll
    for (int j = 0; j < 8; ++j) {
      wv0[j] = r0[j]; wv1[j] = r1[j]; wv2[j] = r2[j]; wv3[j] = r3[j];
    }
  }

  // swizzled float4 read indices for this lane's k-eighth
  int hidx[8];
  #pragma unroll
  for (int j = 0; j < 8; ++j) hidx[j] = (q << 3) | (j ^ q);

  // duty output this lane finalizes (q2=0 -> LDS h write, q2=1 -> global p)
  const int duty = w * 32 + g + 8 * qlow;
  const int jd = (duty >> 2) & 7;
  const int dIdx = (w << 5) | ((jd ^ w) << 2) | (duty & 3);  // swizzled slot
  const float wih0 = W_ih[duty * 3 + 0];
  const float wih1 = W_ih[duty * 3 + 1];
  const float wih2 = W_ih[duty * 3 + 2];

  // init h (swizzled store of h0)
  if (tid < H) {
    const int o = tid;
    const int jo = (o >> 2) & 7;
    const int qo = o >> 5;
    hbuf[0][(qo << 5) | ((jo ^ qo) << 2) | (o & 3)] = h0[o];
  }

  const float* xb = inputs + (size_t)b * T_LEN * 3;
  float* po = p_out + (size_t)b * T_LEN * H + duty;
  __syncthreads();

#define RNN_STEP(CUR, NXT, TT, X0, X1, X2)                                   \
  {                                                                          \
    const float4* h4 = reinterpret_cast<const float4*>(hbuf[CUR]);           \
    float a0 = 0.f, a1 = 0.f, a2 = 0.f, a3 = 0.f;                            \
    _Pragma("unroll") for (int j = 0; j < 8; ++j) {                          \
      const float4 hv = h4[hidx[j]];                                         \
      a0 = fmaf(wv0[j].x, hv.x, a0);                                         \
      a1 = fmaf(wv1[j].x, hv.x, a1);                                         \
      a2 = fmaf(wv2[j].x, hv.x, a2);                                         \
      a3 = fmaf(wv3[j].x, hv.x, a3);                                         \
      a0 = fmaf(wv0[j].y, hv.y, a0);                                         \
      a1 = fmaf(wv1[j].y, hv.y, a1);                                         \
      a2 = fmaf(wv2[j].y, hv.y, a2);                                         \
      a3 = fmaf(wv3[j].y, hv.y, a3);                                         \
      a0 = fmaf(wv0[j].z, hv.z, a0);                                         \
      a1 = fmaf(wv1[j].z, hv.z, a1);                                         \
      a2 = fmaf(wv2[j].z, hv.z, a2);                                         \
      a3 = fmaf(wv3[j].z, hv.z, a3);                                         \
      a0 = fmaf(wv0[j].w, hv.w, a0);                                         \
      a1 = fmaf(wv1[j].w, hv.w, a1);                                         \
      a2 = fmaf(wv2[j].w, hv.w, a2);                                         \
      a3 = fmaf(wv3[j].w, hv.w, a3);                                         \
    }                                                                        \
    a0 = dpp_xor_add<0xB1>(a0); a0 = dpp_xor_add<0x4E>(a0); a0 = xor32_add(a0); \
    a1 = dpp_xor_add<0xB1>(a1); a1 = dpp_xor_add<0x4E>(a1); a1 = xor32_add(a1); \
    a2 = dpp_xor_add<0xB1>(a2); a2 = dpp_xor_add<0x4E>(a2); a2 = xor32_add(a2); \
    a3 = dpp_xor_add<0xB1>(a3); a3 = dpp_xor_add<0x4E>(a3); a3 = xor32_add(a3); \
    const float tot = qlow == 0 ? a0 : qlow == 1 ? a1 : qlow == 2 ? a2 : a3; \
    float hn = fmaf((X2), wih2, fmaf((X1), wih1, fmaf((X0), wih0, tot)));    \
    hn = fmaxf(hn, 0.0f);                                                    \
    if (lane < 32) hbuf[NXT][dIdx] = hn;                                     \
    else           po[(size_t)(TT) * H] = hn;                                \
    asm volatile("s_waitcnt lgkmcnt(0)\n\ts_barrier" ::: "memory");          \
  }

  for (int t = 0; t < T_LEN; t += 2) {
    const float y0 = xb[t * 3 + 0];
    const float y1 = xb[t * 3 + 1];
    const float y2 = xb[t * 3 + 2];
    const float z0 = xb[t * 3 + 3];
    const float z1 = xb[t * 3 + 4];
    const float z2 = xb[t * 3 + 5];
    RNN_STEP(0, 1, t,     y0, y1, y2);
    RNN_STEP(1, 0, t + 1, z0, z1, z2);
  }
#undef RNN_STEP
}

// ---------------------------------------------------------------- cvt + sq
// One wave per (b,t): fp32 p -> bf16 pb, and sq[b,t] = sum(bf16(p)^2)
// (sq from the *rounded* values so the gram diagonal cancels exactly).
__global__ void cvt_kernel(const float* __restrict__ p, unsigned short* __restrict__ pb,
                           float* __restrict__ sq) {
  const int gw = blockIdx.x * 4 + (threadIdx.x >> 6);  // global (b,t) index
  const int lane = threadIdx.x & 63;
  const float4 v = reinterpret_cast<const float4*>(p + (size_t)gw * H)[lane];
  const unsigned short u0 = f32_to_bf16_rne(v.x);
  const unsigned short u1 = f32_to_bf16_rne(v.y);
  const unsigned short u2 = f32_to_bf16_rne(v.z);
  const unsigned short u3 = f32_to_bf16_rne(v.w);
  ushort4 st;
  st.x = u0; st.y = u1; st.z = u2; st.w = u3;
  reinterpret_cast<ushort4*>(pb + (size_t)gw * H)[lane] = st;
  const float r0 = bf16_to_f32(u0), r1 = bf16_to_f32(u1);
  const float r2 = bf16_to_f32(u2), r3 = bf16_to_f32(u3);
  float s = r0 * r0 + r1 * r1 + r2 * r2 + r3 * r3;
  #pragma unroll
  for (int off = 32; off > 0; off >>= 1) s += __shfl_down(s, off, 64);
  if (lane == 0) sq[gw] = s;
}

// ---------------------------------------------------------------- gram + exp
// Per block: one 128x128 tile of corr[b]. 4 waves, each a 64x64 subtile as
// 4x4 grid of 16x16x32 bf16 MFMA tiles. NT gemm: both tiles load identically.
__global__ __launch_bounds__(256) void gram_kernel(
    const unsigned short* __restrict__ pb, const float* __restrict__ sq,
    float* __restrict__ corr) {
  __shared__ unsigned short At[128 * 64];
  __shared__ unsigned short Bt[128 * 64];
  __shared__ float sqT[128];
  __shared__ float sqS[128];

  const int b = blockIdx.y;
  const int t0 = (blockIdx.x >> 3) * 128;
  const int s0 = (blockIdx.x & 7) * 128;
  const int tid = threadIdx.x;

  if (tid < 128) sqT[tid] = sq[b * T_LEN + t0 + tid];
  else           sqS[tid - 128] = sq[b * T_LEN + s0 + (tid - 128)];

  const int lane = tid & 63;
  const int wave = tid >> 6;
  const int wm = wave >> 1;    // 0..1 (t dim)
  const int wn = wave & 1;     // 0..1 (s dim)
  const int m16 = lane & 15;
  const int kg = lane >> 4;    // 0..3

  f32x4 acc[4][4];
  #pragma unroll
  for (int i = 0; i < 4; ++i)
    #pragma unroll
    for (int j = 0; j < 4; ++j) acc[i][j] = (f32x4){0.f, 0.f, 0.f, 0.f};

  const size_t baseT = ((size_t)b * T_LEN + t0) * H;
  const size_t baseS = ((size_t)b * T_LEN + s0) * H;

  for (int kc = 0; kc < 4; ++kc) {
    // stage 128x64 bf16 tiles (16 KB each)
    #pragma unroll
    for (int i = 0; i < 4; ++i) {
      const int c = tid + 256 * i;     // 16-byte chunk id, 0..1023
      const int r = c >> 3;
      const int k8 = c & 7;
      *reinterpret_cast<uint4*>(&At[r * 64 + k8 * 8]) =
          *reinterpret_cast<const uint4*>(pb + baseT + (size_t)r * H + kc * 64 + k8 * 8);
      *reinterpret_cast<uint4*>(&Bt[r * 64 + k8 * 8]) =
          *reinterpret_cast<const uint4*>(pb + baseS + (size_t)r * H + kc * 64 + k8 * 8);
    }
    __syncthreads();

    #pragma unroll
    for (int k32 = 0; k32 < 64; k32 += 32) {
      bf16x8 af[4], bfm[4];
      #pragma unroll
      for (int i = 0; i < 4; ++i)
        af[i] = *reinterpret_cast<const bf16x8*>(
            &At[(wm * 64 + i * 16 + m16) * 64 + k32 + kg * 8]);
      #pragma unroll
      for (int j = 0; j < 4; ++j)
        bfm[j] = *reinterpret_cast<const bf16x8*>(
            &Bt[(wn * 64 + j * 16 + m16) * 64 + k32 + kg * 8]);
      #pragma unroll
      for (int i = 0; i < 4; ++i)
        #pragma unroll
        for (int j = 0; j < 4; ++j)
          acc[i][j] = __builtin_amdgcn_mfma_f32_16x16x32_bf16(af[i], bfm[j], acc[i][j], 0, 0, 0);
    }
    __syncthreads();
  }

  // epilogue: dp = max(sq_t + sq_s - 2G, 0); corr = exp(-dp)
  // C/D layout: col = lane&15, row = (lane>>4)*4 + reg
  #pragma unroll
  for (int i = 0; i < 4; ++i) {
    #pragma unroll
    for (int j = 0; j < 4; ++j) {
      #pragma unroll
      for (int r = 0; r < 4; ++r) {
        const int trow = wm * 64 + i * 16 + kg * 4 + r;
        const int scol = wn * 64 + j * 16 + m16;
        const float dp = fmaxf(sqT[trow] + sqS[scol] - 2.0f * acc[i][j][r], 0.0f);
        corr[((size_t)b * T_LEN + t0 + trow) * T_LEN + s0 + scol] = __expf(-dp);
      }
    }
  }
}

// ---------------------------------------------------------------- launch
extern "C" void kernel_launch(void* const* d_in, const int* in_sizes, int n_in,
                              void* d_out, int out_size, void* d_ws, size_t ws_size,
                              hipStream_t stream) {
  const float* inputs = (const float*)d_in[0];
  const float* W1   = (const float*)d_in[1];
  const float* b1   = (const float*)d_in[2];
  const float* W2   = (const float*)d_in[3];
  const float* b2   = (const float*)d_in[4];
  const float* W_ih = (const float*)d_in[5];
  const float* W_hh = (const float*)d_in[6];

  float* corr = (float*)d_out;                              // [B,T,T]
  float* p = corr + (size_t)B_SZ * T_LEN * T_LEN;           // [B,T,H]

  unsigned short* pb = (unsigned short*)d_ws;               // [B,T,H] bf16 (64 MB)
  float* sq = (float*)((char*)d_ws + (size_t)B_SZ * T_LEN * H * 2);  // [B,T]
  float* h0 = sq + (size_t)B_SZ * T_LEN;                    // [H]

  h0_kernel<<<1, 256, 0, stream>>>(W1, b1, W2, b2, h0);
  rnn_kernel<<<B_SZ, 512, 0, stream>>>(inputs, W_ih, W_hh, h0, p);
  cvt_kernel<<<B_SZ * T_LEN / 4, 256, 0, stream>>>(p, pb, sq);
  gram_kernel<<<dim3(64, B_SZ), 256, 0, stream>>>(pb, sq, corr);
}